// Round 6
// baseline (776.813 us; speedup 1.0000x reference)
//
#include <hip/hip_runtime.h>
#include <hip/hip_bf16.h>
#include <stdint.h>

typedef __attribute__((ext_vector_type(8))) short short8;
typedef __attribute__((ext_vector_type(4))) float f32x4;
typedef __attribute__((ext_vector_type(4))) float float4v;
typedef __attribute__((ext_vector_type(4))) int int4v;

#define MDIM 8192
#define NDIM 11008
#define KDIM 4096
#define NT   (KDIM / 64)      /* 64 K-tiles */
#define NBM2 (MDIM / 256)     /* 32 */
#define NBN2 (NDIM / 256)     /* 43 */

static __device__ __forceinline__ unsigned short f2bf(float f) {
  union { float f; unsigned int u; } v;
  v.f = f;
  unsigned int r = v.u + 0x7FFFu + ((v.u >> 16) & 1u);
  return (unsigned short)(r >> 16);
}

#define GLDS16(g, l) __builtin_amdgcn_global_load_lds(                         \
    (const __attribute__((address_space(1))) void*)(g),                        \
    (__attribute__((address_space(3))) void*)(l), 16, 0, 0)

// ---------------- pass 1: x fp32 -> bf16  AND  qweight -> bf16 (one launch) --
#define XBLOCKS ((MDIM * (size_t)KDIM) / (8 * 256))   /* 16384 */
#define WBLOCKS ((NDIM * (size_t)KDIM) / (8 * 256))   /* 22016 */

__global__ __launch_bounds__(256) void conv_all(
    const float* __restrict__ x, unsigned short* __restrict__ xb,
    const int* __restrict__ qw, const float* __restrict__ scale,
    unsigned short* __restrict__ wb) {
  if (blockIdx.x < XBLOCKS) {
    const size_t i = ((size_t)blockIdx.x * 256 + threadIdx.x) * 8;
    float4v v0 = *(const float4v*)(x + i);
    float4v v1 = *(const float4v*)(x + i + 4);
    short8 o;
#pragma unroll
    for (int e = 0; e < 4; ++e) { o[e] = (short)f2bf(v0[e]); o[4 + e] = (short)f2bf(v1[e]); }
    *(short8*)(xb + i) = o;
  } else {
    const size_t i = (((size_t)blockIdx.x - XBLOCKS) * 256 + threadIdx.x) * 8;
    int4v q0 = *(const int4v*)(qw + i);
    int4v q1 = *(const int4v*)(qw + i + 4);
    const float inv = 1.0f / scale[i >> 8];
    short8 o;
#pragma unroll
    for (int e = 0; e < 4; ++e) {
      o[e]     = (short)f2bf((float)q0[e] * inv);
      o[4 + e] = (short)f2bf((float)q1[e] * inv);
    }
    *(short8*)(wb + i) = o;
  }
}

// ---------------- pass 2: 256x256 barrier-light bf16 GEMM ----------------
// One barrier + one vmcnt(0) per K-tile. All intra-tile ds_reads hit buffer
// `cur` (valid at entry barrier); all staging writes hit `cur^1` (first read
// only after the NEXT entry barrier). Per-wave reads retire before the exit
// barrier, so buffer reuse at tile t+2 is safe.
__global__ __launch_bounds__(512, 2) void gemm256(
    const unsigned short* __restrict__ xa,
    const unsigned short* __restrict__ wb,
    const float* __restrict__ bias,
    float* __restrict__ out)
{
  __shared__ unsigned char lds[131072];
  unsigned char* ldsA = lds;            // [2][32768]: 256 rows x 64 bf16, swizzled slots
  unsigned char* ldsB = lds + 65536;    // [2][32768]

  const int t = threadIdx.x;
  const int lane = t & 63;
  const int w = t >> 6;        // wave 0..7
  const int wr = w >> 2;       // 0..1  (A half)
  const int wc = w & 3;        // 0..3  (B quarter)
  const int lh = lane >> 4;    // 0..3
  const int l15 = lane & 15;
  const int l7 = lane & 7;
  const int lr = lane >> 3;    // 0..7 staging row within 8-row strip

  // XCD-bijective swizzle: 1376 = 8 * 172
  const int bid = blockIdx.x;
  const int swz = (bid & 7) * (NBM2 * NBN2 / 8) + (bid >> 3);
  const int bm = swz / NBN2;
  const int bn = swz % NBN2;

  // per-lane LDS read base: row-part l15*128, slot ((ks*4+lh)^l7)<<4; ks flips bit 6
  const int rdBase0 = l15 * 128 + ((lh ^ l7) << 4);

  // staging: linear LDS dest (base+lane*16) <- pre-swizzled global source
  const size_t srcOff = (size_t)lr * KDIM + ((l7 ^ lr) << 3);

  const unsigned short* aS = xa + ((size_t)(bm * 256 + wr * 128 + wc * 8)) * KDIM + srcOff;
  const unsigned short* bS = wb + ((size_t)(bn * 256 + w * 32)) * KDIM + srcOff;
  const int aDst = (wr * 128 + wc * 8) * 128;   // + q*4096 + cur*32768
  const int bDst = (w * 32) * 128;              // + c*1024 + cur*32768

  float bias_v[4];
#pragma unroll
  for (int n = 0; n < 4; ++n) bias_v[n] = bias[bn * 256 + wc * 64 + n * 16 + l15];

  f32x4 acc[8][4];
#pragma unroll
  for (int m = 0; m < 8; ++m)
#pragma unroll
    for (int n = 0; n < 4; ++n) acc[m][n] = (f32x4){0.f, 0.f, 0.f, 0.f};

#define STAGE_B4(cur, kt) {                                                    \
  _Pragma("unroll")                                                            \
  for (int c = 0; c < 4; ++c)                                                  \
    GLDS16(bS + (size_t)(c * 8) * KDIM + (kt) * 64,                            \
           ldsB + (cur) * 32768 + bDst + c * 1024); }
#define STAGE_A1(cur, kt, q)                                                   \
    GLDS16(aS + (size_t)((q) * 32) * KDIM + (kt) * 64,                         \
           ldsA + (cur) * 32768 + aDst + (q) * 4096);

#define RD_A(cur, m, ks) (*(const short8*)(ldsA + (cur) * 32768 + wr * 16384 + \
                          (m) * 2048 + (rdBase0 ^ ((ks) * 64))))
#define RD_B(cur, n, ks) (*(const short8*)(ldsB + (cur) * 32768 + wc * 8192 +  \
                          (n) * 2048 + (rdBase0 ^ ((ks) * 64))))

#define MFMA16(AF, BF, MOFF) {                                                 \
  _Pragma("unroll")                                                            \
  for (int i = 0; i < 4; ++i)                                                  \
    _Pragma("unroll")                                                          \
    for (int n = 0; n < 4; ++n)                                                \
      acc[(MOFF) + i][n] = __builtin_amdgcn_mfma_f32_16x16x32_bf16(            \
          AF[i], BF[n], acc[(MOFF) + i][n], 0, 0, 0); }

// One tile: interleaved {stage-issue, ds_read-next, MFMA-current}; no internal
// barriers — compiler schedules with rolling lgkmcnt; waves free-run.
#define TILE(cur, kt, DOSTAGE) {                                               \
  short8 A0[4], A1[4], A2[4], A3[4], B0[4], B1[4];                             \
  if (DOSTAGE) {                                                               \
    STAGE_B4((cur) ^ 1, (kt) + 1);                                             \
    STAGE_A1((cur) ^ 1, (kt) + 1, 0);                                          \
    STAGE_A1((cur) ^ 1, (kt) + 1, 1);                                          \
  }                                                                            \
  _Pragma("unroll")                                                            \
  for (int i = 0; i < 4; ++i) A0[i] = RD_A(cur, i, 0);                         \
  _Pragma("unroll")                                                            \
  for (int n = 0; n < 4; ++n) B0[n] = RD_B(cur, n, 0);                         \
  if (DOSTAGE) {                                                               \
    STAGE_A1((cur) ^ 1, (kt) + 1, 2);                                          \
    STAGE_A1((cur) ^ 1, (kt) + 1, 3);                                          \
  }                                                                            \
  _Pragma("unroll")                                                            \
  for (int i = 0; i < 4; ++i) A1[i] = RD_A(cur, 4 + i, 0);                     \
  __builtin_amdgcn_s_setprio(1);                                               \
  MFMA16(A0, B0, 0)                                                            \
  __builtin_amdgcn_s_setprio(0);                                               \
  _Pragma("unroll")                                                            \
  for (int i = 0; i < 4; ++i) A2[i] = RD_A(cur, i, 1);                         \
  _Pragma("unroll")                                                            \
  for (int n = 0; n < 4; ++n) B1[n] = RD_B(cur, n, 1);                         \
  __builtin_amdgcn_s_setprio(1);                                               \
  MFMA16(A1, B0, 4)                                                            \
  __builtin_amdgcn_s_setprio(0);                                               \
  _Pragma("unroll")                                                            \
  for (int i = 0; i < 4; ++i) A3[i] = RD_A(cur, 4 + i, 1);                     \
  __builtin_amdgcn_s_setprio(1);                                               \
  MFMA16(A2, B1, 0)                                                            \
  MFMA16(A3, B1, 4)                                                            \
  __builtin_amdgcn_s_setprio(0);                                               \
  asm volatile("s_waitcnt vmcnt(0)" ::: "memory");                             \
  __builtin_amdgcn_s_barrier(); }

  // prologue: stage tile 0, drain, barrier
  STAGE_B4(0, 0);
  STAGE_A1(0, 0, 0);
  STAGE_A1(0, 0, 1);
  STAGE_A1(0, 0, 2);
  STAGE_A1(0, 0, 3);
  asm volatile("s_waitcnt vmcnt(0)" ::: "memory");
  __builtin_amdgcn_s_barrier();

  for (int kt = 0; kt < NT - 2; kt += 2) {
    TILE(0, kt, 1)
    TILE(1, kt + 1, 1)
  }
  TILE(0, NT - 2, 1)
  TILE(1, NT - 1, 0)

  // epilogue: bias + non-temporal fp32 store (keeps L2 clean for A/B panels)
#pragma unroll
  for (int m = 0; m < 8; ++m) {
    const int row0 = bm * 256 + wr * 128 + m * 16 + lh * 4;
#pragma unroll
    for (int n = 0; n < 4; ++n) {
      const int col = bn * 256 + wc * 64 + n * 16 + l15;
      const float bv_ = bias_v[n];
#pragma unroll
      for (int j = 0; j < 4; ++j)
        __builtin_nontemporal_store(acc[m][n][j] + bv_,
                                    &out[(size_t)(row0 + j) * NDIM + col]);
    }
  }
#undef TILE
#undef MFMA16
#undef RD_A
#undef RD_B
#undef STAGE_A1
#undef STAGE_B4
}

// ---------------- fallback: fused single-pass (round-1 kernel) ----------------
__global__ __launch_bounds__(256, 2) void clinear_fused(
    const float* __restrict__ x,
    const int* __restrict__ qw,
    const float* __restrict__ scale,
    const float* __restrict__ bias,
    float* __restrict__ out)
{
  __shared__ unsigned char ldsA[128 * 64 * 2];
  __shared__ unsigned char ldsB[128 * 64 * 2];

  const int t = threadIdx.x;
  const int lane = t & 63;
  const int wave = t >> 6;
  const int wr = wave >> 1;
  const int wc = wave & 1;

  const int NBN = NDIM / 128;
  const int bid = blockIdx.x;
  const int cpx = ((MDIM / 128) * NBN) >> 3;
  const int swz = (bid & 7) * cpx + (bid >> 3);
  const int bm = swz / NBN;
  const int bn = swz % NBN;

  const int srow = t >> 1;
  const int shalf = t & 1;
  const float* aptr = x  + (size_t)(bm * 128 + srow) * KDIM + shalf * 32;
  const int*   bptr = qw + (size_t)(bn * 128 + srow) * KDIM + shalf * 32;
  const float* sptr = scale + (size_t)(bn * 128 + srow) * (KDIM / 256);
  const int arx = srow & 7;

  f32x4 acc[4][4];
#pragma unroll
  for (int i = 0; i < 4; ++i)
#pragma unroll
    for (int j = 0; j < 4; ++j)
      acc[i][j] = (f32x4){0.f, 0.f, 0.f, 0.f};

  float bias_v[4];
#pragma unroll
  for (int n = 0; n < 4; ++n)
    bias_v[n] = bias[bn * 128 + wc * 64 + n * 16 + (lane & 15)];

  for (int kt = 0; kt < KDIM / 64; ++kt) {
    const int k0 = kt * 64;
    float4v av[8];
    int4v   bv[8];
#pragma unroll
    for (int j = 0; j < 8; ++j) av[j] = *(const float4v*)(aptr + k0 + 4 * j);
#pragma unroll
    for (int j = 0; j < 8; ++j) bv[j] = *(const int4v*)(bptr + k0 + 4 * j);
    const float inv = 1.0f / sptr[k0 >> 8];

    __syncthreads();
#pragma unroll
    for (int c = 0; c < 4; ++c) {
      short8 pa, pb;
#pragma unroll
      for (int e = 0; e < 8; ++e) {
        const int v = c * 8 + e;
        pa[e] = (short)f2bf(av[v >> 2][v & 3]);
        pb[e] = (short)f2bf((float)bv[v >> 2][v & 3] * inv);
      }
      const int cc = shalf * 4 + c;
      *(short8*)(ldsA + srow * 128 + ((cc ^ arx) << 4)) = pa;
      *(short8*)(ldsB + srow * 128 + ((cc ^ arx) << 4)) = pb;
    }
    __syncthreads();

    short8 af[4][2], bfr[4][2];
#pragma unroll
    for (int m = 0; m < 4; ++m) {
      const int r = wr * 64 + m * 16 + (lane & 15);
      const int rx = r & 7;
#pragma unroll
      for (int ks = 0; ks < 2; ++ks) {
        const int ch = ks * 4 + (lane >> 4);
        af[m][ks] = *(const short8*)(ldsA + r * 128 + ((ch ^ rx) << 4));
      }
    }
#pragma unroll
    for (int n = 0; n < 4; ++n) {
      const int r = wc * 64 + n * 16 + (lane & 15);
      const int rx = r & 7;
#pragma unroll
      for (int ks = 0; ks < 2; ++ks) {
        const int ch = ks * 4 + (lane >> 4);
        bfr[n][ks] = *(const short8*)(ldsB + r * 128 + ((ch ^ rx) << 4));
      }
    }
#pragma unroll
    for (int ks = 0; ks < 2; ++ks)
#pragma unroll
      for (int m = 0; m < 4; ++m)
#pragma unroll
        for (int n = 0; n < 4; ++n)
          acc[m][n] = __builtin_amdgcn_mfma_f32_16x16x32_bf16(
              af[m][ks], bfr[n][ks], acc[m][n], 0, 0, 0);
  }

#pragma unroll
  for (int m = 0; m < 4; ++m) {
    const int row0 = bm * 128 + wr * 64 + m * 16 + (lane >> 4) * 4;
#pragma unroll
    for (int n = 0; n < 4; ++n) {
      const int col = bn * 128 + wc * 64 + n * 16 + (lane & 15);
      const float bv_ = bias_v[n];
#pragma unroll
      for (int j = 0; j < 4; ++j)
        out[(size_t)(row0 + j) * NDIM + col] = acc[m][n][j] + bv_;
    }
  }
}

extern "C" void kernel_launch(void* const* d_in, const int* in_sizes, int n_in,
                              void* d_out, int out_size, void* d_ws, size_t ws_size,
                              hipStream_t stream) {
  const float* x     = (const float*)d_in[0];
  const int*   qw    = (const int*)d_in[1];
  const float* scale = (const float*)d_in[2];
  const float* bias  = (const float*)d_in[3];
  float* out = (float*)d_out;

  const size_t needX = (size_t)MDIM * KDIM * sizeof(unsigned short);
  const size_t needW = (size_t)NDIM * KDIM * sizeof(unsigned short);

  if (ws_size >= needX + needW) {
    unsigned short* xb   = (unsigned short*)d_ws;
    unsigned short* wbuf = (unsigned short*)((char*)d_ws + needX);
    hipLaunchKernelGGL(conv_all, dim3(XBLOCKS + WBLOCKS), dim3(256), 0, stream,
                       x, xb, qw, scale, wbuf);
    hipLaunchKernelGGL(gemm256, dim3(NBM2 * NBN2), dim3(512), 0, stream,
                       xb, wbuf, bias, out);
  } else {
    hipLaunchKernelGGL(clinear_fused, dim3((MDIM / 128) * (NDIM / 128)), dim3(256),
                       0, stream, x, qw, scale, bias, out);
  }
}

// Round 7
// 662.137 us; speedup vs baseline: 1.1732x; 1.1732x over previous
//
#include <hip/hip_runtime.h>
#include <hip/hip_bf16.h>
#include <stdint.h>

typedef __attribute__((ext_vector_type(8))) short short8;
typedef __attribute__((ext_vector_type(4))) float f32x4;
typedef __attribute__((ext_vector_type(4))) float float4v;
typedef __attribute__((ext_vector_type(4))) int int4v;

#define MDIM 8192
#define NDIM 11008
#define KDIM 4096
#define BKI  128               /* i8 K-tile (bytes per LDS row) */
#define NTI  (KDIM / BKI)      /* 32 K-tiles */
#define NBMI (MDIM / 256)      /* 32 */
#define NBNI (NDIM / 128)      /* 86 */

// ws layout (bytes)
#define XQ_OFF  0ull
#define WQ_OFF  ((size_t)MDIM * KDIM)                 /* 33554432 */
#define SXT_OFF (WQ_OFF + (size_t)NDIM * KDIM)        /* + 45088768 */
#define SWI_OFF (SXT_OFF + 16ull * MDIM * 4)          /* + 524288 */
#define WS_NEED (SWI_OFF + (size_t)NDIM * 16 * 4)     /* ~79.9 MB */

static __device__ __forceinline__ unsigned short f2bf(float f) {
  union { float f; unsigned int u; } v;
  v.f = f;
  unsigned int r = v.u + 0x7FFFu + ((v.u >> 16) & 1u);
  return (unsigned short)(r >> 16);
}

#define GLDS16(g, l) __builtin_amdgcn_global_load_lds(                         \
    (const __attribute__((address_space(1))) void*)(g),                        \
    (__attribute__((address_space(3))) void*)(l), 16, 0, 0)

// ---------------- pass 1a: x fp32 -> int8 per-(row, G=256) group ----------------
// one block per row; thread t handles elems t*16..t*16+15; group = 16 threads
__global__ __launch_bounds__(256) void quant_x(const float* __restrict__ x,
                                               char* __restrict__ xq,
                                               float* __restrict__ sxT) {
  const int row = blockIdx.x;
  const int t = threadIdx.x;
  const float* p = x + (size_t)row * KDIM + t * 16;
  float4v v[4];
#pragma unroll
  for (int c = 0; c < 4; ++c) v[c] = *(const float4v*)(p + c * 4);
  float amax = 0.f;
#pragma unroll
  for (int c = 0; c < 4; ++c)
#pragma unroll
    for (int e = 0; e < 4; ++e) amax = fmaxf(amax, fabsf(v[c][e]));
#pragma unroll
  for (int d = 1; d < 16; d <<= 1) amax = fmaxf(amax, __shfl_xor(amax, d));
  amax = fmaxf(amax, 1e-20f);
  if ((t & 15) == 0)
    sxT[(size_t)(t >> 4) * MDIM + row] = amax * (1.0f / 127.0f);
  const float inv = 127.0f / amax;
  int4v o;
#pragma unroll
  for (int c = 0; c < 4; ++c) {
    unsigned int r = 0;
#pragma unroll
    for (int e = 0; e < 4; ++e) {
      int q = __float2int_rn(v[c][e] * inv);
      r |= ((unsigned int)(q & 255)) << (8 * e);
    }
    o[c] = (int)r;
  }
  *(int4v*)(xq + (size_t)row * KDIM + t * 16) = o;
}

// ---------------- pass 1b: qweight int32 -> int8 pack, + 1/scale ----------------
__global__ __launch_bounds__(256) void pack_w(const int* __restrict__ qw,
                                              const float* __restrict__ scale,
                                              char* __restrict__ wq,
                                              float* __restrict__ swinv) {
  const int row = blockIdx.x;
  const int t = threadIdx.x;
  const int* p = qw + (size_t)row * KDIM + t * 16;
  int4v v[4];
#pragma unroll
  for (int c = 0; c < 4; ++c) v[c] = *(const int4v*)(p + c * 4);
  int4v o;
#pragma unroll
  for (int c = 0; c < 4; ++c) {
    unsigned int r = 0;
#pragma unroll
    for (int e = 0; e < 4; ++e) r |= ((unsigned int)(v[c][e] & 255)) << (8 * e);
    o[c] = (int)r;
  }
  *(int4v*)(wq + (size_t)row * KDIM + t * 16) = o;
  if ((t & 15) == 0) {
    const size_t si = (size_t)row * 16 + (t >> 4);
    swinv[si] = 1.0f / scale[si];
  }
}

// ---------------- pass 2: 256x128 i8 GEMM, BK=128, group-wise f32 fixup ------
__global__ __launch_bounds__(512, 2) void gemm_i8(
    const char* __restrict__ xq, const char* __restrict__ wq,
    const float* __restrict__ sxT, const float* __restrict__ swinv,
    const float* __restrict__ bias, float* __restrict__ out)
{
  __shared__ unsigned char lds[98304];
  unsigned char* ldsA = lds;            // [2][32768]: 256 rows x 128B, swizzled granules
  unsigned char* ldsB = lds + 65536;    // [2][16384]: 128 rows x 128B

  const int t = threadIdx.x;
  const int lane = t & 63;
  const int w = t >> 6;        // wave 0..7
  const int wr = w >> 1;       // 0..3  (A 64-row quarter)
  const int wc = w & 1;        // 0..1  (B 64-col half)
  const int lh = lane >> 4;    // 0..3
  const int l15 = lane & 15;
  const int l7 = lane & 7;
  const int lr = lane >> 3;    // 0..7 staging row within 8-row strip

  // XCD-bijective swizzle: 2752 = 8 * 344
  const int bid = blockIdx.x;
  const int swz = (bid & 7) * (NBMI * NBNI / 8) + (bid >> 3);
  const int bm = swz / NBNI;
  const int bn = swz % NBNI;

  // per-lane read base: row l15 (*128B), granule (lh ^ l7)*16B; ks flips bit 6
  const int rdBase0 = l15 * 128 + ((lh ^ l7) << 4);
  // staging: linear LDS dest <- pre-swizzled global source (granule = l7 ^ lr)
  const size_t srcOff = (size_t)lr * KDIM + ((l7 ^ lr) << 4);

  const char* aS = xq + ((size_t)(bm * 256 + w * 32)) * KDIM + srcOff;
  const char* bS = wq + ((size_t)(bn * 128 + w * 16)) * KDIM + srcOff;

  float bias_v[4];
#pragma unroll
  for (int n = 0; n < 4; ++n) bias_v[n] = bias[bn * 128 + wc * 64 + n * 16 + l15];

  f32x4 accf[4][4];
  int4v acci[4][4];
#pragma unroll
  for (int m = 0; m < 4; ++m)
#pragma unroll
    for (int n = 0; n < 4; ++n) {
      accf[m][n] = (f32x4){0.f, 0.f, 0.f, 0.f};
      acci[m][n] = (int4v){0, 0, 0, 0};
    }

#define STAGE6(cur, kt) {                                                      \
  GLDS16(bS + (size_t)0 * 8 * KDIM + (kt) * BKI, ldsB + (cur) * 16384 + w * 2048);        \
  GLDS16(bS + (size_t)1 * 8 * KDIM + (kt) * BKI, ldsB + (cur) * 16384 + w * 2048 + 1024); \
  _Pragma("unroll")                                                            \
  for (int s = 0; s < 4; ++s)                                                  \
    GLDS16(aS + (size_t)s * 8 * KDIM + (kt) * BKI,                             \
           ldsA + (cur) * 32768 + w * 4096 + s * 1024); }

#define RD_A(cur, m, ks) (*(const int4v*)(ldsA + (cur) * 32768 + wr * 8192 +   \
                          (m) * 2048 + (rdBase0 ^ ((ks) * 64))))
#define RD_B(cur, n, ks) (*(const int4v*)(ldsB + (cur) * 16384 + wc * 8192 +   \
                          (n) * 2048 + (rdBase0 ^ ((ks) * 64))))

// One K-tile (BK=128): 2 ks-halves of 16 MFMA; one vmcnt(0)+barrier per tile.
// DOFIX on odd kt: apply group scales (g = kt>>1) to acci -> accf, reset acci.
#define TILE(cur, kt, DOSTAGE, DOFIX) {                                        \
  if (DOSTAGE) STAGE6((cur) ^ 1, (kt) + 1);                                    \
  int4v a0[4], b0[4], a1[4], b1[4];                                            \
  _Pragma("unroll")                                                            \
  for (int i = 0; i < 4; ++i) a0[i] = RD_A(cur, i, 0);                         \
  _Pragma("unroll")                                                            \
  for (int n = 0; n < 4; ++n) b0[n] = RD_B(cur, n, 0);                         \
  float4v sxv[4]; float swv[4];                                                \
  if (DOFIX) {                                                                 \
    const int g = (kt) >> 1;                                                   \
    _Pragma("unroll")                                                          \
    for (int m = 0; m < 4; ++m)                                                \
      sxv[m] = *(const float4v*)(sxT + (size_t)g * MDIM + bm * 256 + wr * 64 + \
                                 m * 16 + lh * 4);                             \
    _Pragma("unroll")                                                          \
    for (int n = 0; n < 4; ++n)                                                \
      swv[n] = swinv[(size_t)(bn * 128 + wc * 64 + n * 16 + l15) * 16 + g];    \
  }                                                                            \
  __builtin_amdgcn_s_setprio(1);                                               \
  _Pragma("unroll")                                                            \
  for (int m = 0; m < 4; ++m)                                                  \
    _Pragma("unroll")                                                          \
    for (int n = 0; n < 4; ++n)                                                \
      acci[m][n] = __builtin_amdgcn_mfma_i32_16x16x64_i8(a0[m], b0[n],         \
                                                         acci[m][n], 0, 0, 0); \
  __builtin_amdgcn_s_setprio(0);                                               \
  _Pragma("unroll")                                                            \
  for (int i = 0; i < 4; ++i) a1[i] = RD_A(cur, i, 1);                         \
  _Pragma("unroll")                                                            \
  for (int n = 0; n < 4; ++n) b1[n] = RD_B(cur, n, 1);                         \
  __builtin_amdgcn_s_setprio(1);                                               \
  _Pragma("unroll")                                                            \
  for (int m = 0; m < 4; ++m)                                                  \
    _Pragma("unroll")                                                          \
    for (int n = 0; n < 4; ++n)                                                \
      acci[m][n] = __builtin_amdgcn_mfma_i32_16x16x64_i8(a1[m], b1[n],         \
                                                         acci[m][n], 0, 0, 0); \
  __builtin_amdgcn_s_setprio(0);                                               \
  if (DOFIX) {                                                                 \
    _Pragma("unroll")                                                          \
    for (int m = 0; m < 4; ++m)                                                \
      _Pragma("unroll")                                                        \
      for (int n = 0; n < 4; ++n) {                                            \
        _Pragma("unroll")                                                      \
        for (int j = 0; j < 4; ++j)                                            \
          accf[m][n][j] += (float)acci[m][n][j] * (sxv[m][j] * swv[n]);        \
        acci[m][n] = (int4v){0, 0, 0, 0};                                      \
      }                                                                        \
  }                                                                            \
  asm volatile("s_waitcnt vmcnt(0)" ::: "memory");                             \
  __builtin_amdgcn_s_barrier(); }

  // prologue: stage tile 0, drain, barrier
  STAGE6(0, 0);
  asm volatile("s_waitcnt vmcnt(0)" ::: "memory");
  __builtin_amdgcn_s_barrier();

  for (int kt = 0; kt < NTI - 2; kt += 2) {
    TILE(0, kt, 1, 0)
    TILE(1, kt + 1, 1, 1)
  }
  TILE(0, NTI - 2, 1, 0)
  TILE(1, NTI - 1, 0, 1)

  // epilogue: bias + fp32 store (C/D map: col=lane&15, row=(lane>>4)*4+j)
#pragma unroll
  for (int m = 0; m < 4; ++m) {
    const int row0 = bm * 256 + wr * 64 + m * 16 + lh * 4;
#pragma unroll
    for (int n = 0; n < 4; ++n) {
      const int col = bn * 128 + wc * 64 + n * 16 + l15;
      const float bv_ = bias_v[n];
#pragma unroll
      for (int j = 0; j < 4; ++j)
        out[(size_t)(row0 + j) * NDIM + col] = accf[m][n][j] + bv_;
    }
  }
#undef TILE
#undef RD_A
#undef RD_B
#undef STAGE6
}

// ---------------- fallback: fused single-pass (round-1 kernel) ----------------
__global__ __launch_bounds__(256, 2) void clinear_fused(
    const float* __restrict__ x,
    const int* __restrict__ qw,
    const float* __restrict__ scale,
    const float* __restrict__ bias,
    float* __restrict__ out)
{
  __shared__ unsigned char ldsA[128 * 64 * 2];
  __shared__ unsigned char ldsB[128 * 64 * 2];

  const int t = threadIdx.x;
  const int lane = t & 63;
  const int wave = t >> 6;
  const int wr = wave >> 1;
  const int wc = wave & 1;

  const int NBN = NDIM / 128;
  const int bid = blockIdx.x;
  const int cpx = ((MDIM / 128) * NBN) >> 3;
  const int swz = (bid & 7) * cpx + (bid >> 3);
  const int bm = swz / NBN;
  const int bn = swz % NBN;

  const int srow = t >> 1;
  const int shalf = t & 1;
  const float* aptr = x  + (size_t)(bm * 128 + srow) * KDIM + shalf * 32;
  const int*   bptr = qw + (size_t)(bn * 128 + srow) * KDIM + shalf * 32;
  const float* sptr = scale + (size_t)(bn * 128 + srow) * (KDIM / 256);
  const int arx = srow & 7;

  f32x4 acc[4][4];
#pragma unroll
  for (int i = 0; i < 4; ++i)
#pragma unroll
    for (int j = 0; j < 4; ++j)
      acc[i][j] = (f32x4){0.f, 0.f, 0.f, 0.f};

  float bias_v[4];
#pragma unroll
  for (int n = 0; n < 4; ++n)
    bias_v[n] = bias[bn * 128 + wc * 64 + n * 16 + (lane & 15)];

  for (int kt = 0; kt < KDIM / 64; ++kt) {
    const int k0 = kt * 64;
    float4v av[8];
    int4v   bv[8];
#pragma unroll
    for (int j = 0; j < 8; ++j) av[j] = *(const float4v*)(aptr + k0 + 4 * j);
#pragma unroll
    for (int j = 0; j < 8; ++j) bv[j] = *(const int4v*)(bptr + k0 + 4 * j);
    const float inv = 1.0f / sptr[k0 >> 8];

    __syncthreads();
#pragma unroll
    for (int c = 0; c < 4; ++c) {
      short8 pa, pb;
#pragma unroll
      for (int e = 0; e < 8; ++e) {
        const int v = c * 8 + e;
        pa[e] = (short)f2bf(av[v >> 2][v & 3]);
        pb[e] = (short)f2bf((float)bv[v >> 2][v & 3] * inv);
      }
      const int cc = shalf * 4 + c;
      *(short8*)(ldsA + srow * 128 + ((cc ^ arx) << 4)) = pa;
      *(short8*)(ldsB + srow * 128 + ((cc ^ arx) << 4)) = pb;
    }
    __syncthreads();

    short8 af[4][2], bfr[4][2];
#pragma unroll
    for (int m = 0; m < 4; ++m) {
      const int r = wr * 64 + m * 16 + (lane & 15);
      const int rx = r & 7;
#pragma unroll
      for (int ks = 0; ks < 2; ++ks) {
        const int ch = ks * 4 + (lane >> 4);
        af[m][ks] = *(const short8*)(ldsA + r * 128 + ((ch ^ rx) << 4));
      }
    }
#pragma unroll
    for (int n = 0; n < 4; ++n) {
      const int r = wc * 64 + n * 16 + (lane & 15);
      const int rx = r & 7;
#pragma unroll
      for (int ks = 0; ks < 2; ++ks) {
        const int ch = ks * 4 + (lane >> 4);
        bfr[n][ks] = *(const short8*)(ldsB + r * 128 + ((ch ^ rx) << 4));
      }
    }
#pragma unroll
    for (int ks = 0; ks < 2; ++ks)
#pragma unroll
      for (int m = 0; m < 4; ++m)
#pragma unroll
        for (int n = 0; n < 4; ++n)
          acc[m][n] = __builtin_amdgcn_mfma_f32_16x16x32_bf16(
              af[m][ks], bfr[n][ks], acc[m][n], 0, 0, 0);
  }

#pragma unroll
  for (int m = 0; m < 4; ++m) {
    const int row0 = bm * 128 + wr * 64 + m * 16 + (lane >> 4) * 4;
#pragma unroll
    for (int n = 0; n < 4; ++n) {
      const int col = bn * 128 + wc * 64 + n * 16 + (lane & 15);
      const float bv_ = bias_v[n];
#pragma unroll
      for (int j = 0; j < 4; ++j)
        out[(size_t)(row0 + j) * NDIM + col] = acc[m][n][j] + bv_;
    }
  }
}

extern "C" void kernel_launch(void* const* d_in, const int* in_sizes, int n_in,
                              void* d_out, int out_size, void* d_ws, size_t ws_size,
                              hipStream_t stream) {
  const float* x     = (const float*)d_in[0];
  const int*   qw    = (const int*)d_in[1];
  const float* scale = (const float*)d_in[2];
  const float* bias  = (const float*)d_in[3];
  float* out = (float*)d_out;

  if (ws_size >= WS_NEED) {
    char*  xqb  = (char*)d_ws + XQ_OFF;
    char*  wqb  = (char*)d_ws + WQ_OFF;
    float* sxT  = (float*)((char*)d_ws + SXT_OFF);
    float* swi  = (float*)((char*)d_ws + SWI_OFF);
    hipLaunchKernelGGL(quant_x, dim3(MDIM), dim3(256), 0, stream, x, xqb, sxT);
    hipLaunchKernelGGL(pack_w, dim3(NDIM), dim3(256), 0, stream, qw, scale, wqb, swi);
    hipLaunchKernelGGL(gemm_i8, dim3(NBMI * NBNI), dim3(512), 0, stream,
                       xqb, wqb, sxT, swi, bias, out);
  } else {
    hipLaunchKernelGGL(clinear_fused, dim3((MDIM / 128) * (NDIM / 128)), dim3(256),
                       0, stream, x, qw, scale, bias, out);
  }
}

// Round 8
// 640.511 us; speedup vs baseline: 1.2128x; 1.0338x over previous
//
#include <hip/hip_runtime.h>
#include <hip/hip_bf16.h>
#include <stdint.h>

typedef __attribute__((ext_vector_type(8))) short short8;
typedef __attribute__((ext_vector_type(4))) float f32x4;
typedef __attribute__((ext_vector_type(4))) float float4v;
typedef __attribute__((ext_vector_type(4))) int int4v;

#define MDIM 8192
#define NDIM 11008
#define KDIM 4096
#define BKI  128               /* i8 K-tile (bytes per LDS row) */
#define NTI  (KDIM / BKI)      /* 32 K-tiles */
#define NBMI (MDIM / 128)      /* 64 */
#define NBNI (NDIM / 128)      /* 86 */

// ws layout (bytes)
#define XQ_OFF  0ull
#define WQ_OFF  ((size_t)MDIM * KDIM)                 /* 33554432 */
#define SXT_OFF (WQ_OFF + (size_t)NDIM * KDIM)        /* + 45088768 */
#define SWI_OFF (SXT_OFF + 16ull * MDIM * 4)          /* + 524288 */
#define WS_NEED (SWI_OFF + (size_t)NDIM * 16 * 4)     /* ~79.9 MB */

static __device__ __forceinline__ unsigned short f2bf(float f) {
  union { float f; unsigned int u; } v;
  v.f = f;
  unsigned int r = v.u + 0x7FFFu + ((v.u >> 16) & 1u);
  return (unsigned short)(r >> 16);
}

#define GLDS16(g, l) __builtin_amdgcn_global_load_lds(                         \
    (const __attribute__((address_space(1))) void*)(g),                        \
    (__attribute__((address_space(3))) void*)(l), 16, 0, 0)

// ---------------- pass 1 (fused): x -> int8 groups  |  qweight -> int8 pack --
// blocks [0, MDIM): quantize x row; blocks [MDIM, MDIM+NDIM): pack w row.
__global__ __launch_bounds__(256) void prep_all(
    const float* __restrict__ x, char* __restrict__ xq, float* __restrict__ sxT,
    const int* __restrict__ qw, const float* __restrict__ scale,
    char* __restrict__ wq, float* __restrict__ swinv) {
  const int t = threadIdx.x;
  if (blockIdx.x < MDIM) {
    const int row = blockIdx.x;
    const float* p = x + (size_t)row * KDIM + t * 16;
    float4v v[4];
#pragma unroll
    for (int c = 0; c < 4; ++c) v[c] = *(const float4v*)(p + c * 4);
    float amax = 0.f;
#pragma unroll
    for (int c = 0; c < 4; ++c)
#pragma unroll
      for (int e = 0; e < 4; ++e) amax = fmaxf(amax, fabsf(v[c][e]));
#pragma unroll
    for (int d = 1; d < 16; d <<= 1) amax = fmaxf(amax, __shfl_xor(amax, d));
    amax = fmaxf(amax, 1e-20f);
    if ((t & 15) == 0)
      sxT[(size_t)(t >> 4) * MDIM + row] = amax * (1.0f / 127.0f);
    const float inv = 127.0f / amax;
    int4v o;
#pragma unroll
    for (int c = 0; c < 4; ++c) {
      unsigned int r = 0;
#pragma unroll
      for (int e = 0; e < 4; ++e) {
        int q = __float2int_rn(v[c][e] * inv);
        r |= ((unsigned int)(q & 255)) << (8 * e);
      }
      o[c] = (int)r;
    }
    *(int4v*)(xq + (size_t)row * KDIM + t * 16) = o;
  } else {
    const int row = blockIdx.x - MDIM;
    const int* p = qw + (size_t)row * KDIM + t * 16;
    int4v v[4];
#pragma unroll
    for (int c = 0; c < 4; ++c) v[c] = *(const int4v*)(p + c * 4);
    int4v o;
#pragma unroll
    for (int c = 0; c < 4; ++c) {
      unsigned int r = 0;
#pragma unroll
      for (int e = 0; e < 4; ++e) r |= ((unsigned int)(v[c][e] & 255)) << (8 * e);
      o[c] = (int)r;
    }
    *(int4v*)(wq + (size_t)row * KDIM + t * 16) = o;
    if ((t & 15) == 0) {
      const size_t si = (size_t)row * 16 + (t >> 4);
      swinv[si] = 1.0f / scale[si];
    }
  }
}

// ---------------- pass 2: 128x128 i8 GEMM, BK=128, 2 blocks/CU ----------------
// 4 waves; wave tile 64x64. 64 KiB LDS -> two independent blocks per CU whose
// barrier stalls interleave (the r7 256x128 version was 1 block/CU lockstep).
__global__ __launch_bounds__(256, 2) void gemm_i8(
    const char* __restrict__ xq, const char* __restrict__ wq,
    const float* __restrict__ sxT, const float* __restrict__ swinv,
    const float* __restrict__ bias, float* __restrict__ out)
{
  __shared__ unsigned char lds[65536];
  unsigned char* ldsA = lds;            // [2][16384]: 128 rows x 128B, swizzled granules
  unsigned char* ldsB = lds + 32768;    // [2][16384]

  const int t = threadIdx.x;
  const int lane = t & 63;
  const int w = t >> 6;        // wave 0..3
  const int wr = w >> 1;       // 0..1  (A 64-row half)
  const int wc = w & 1;        // 0..1  (B 64-col half)
  const int lh = lane >> 4;    // 0..3
  const int l15 = lane & 15;
  const int l7 = lane & 7;
  const int lr = lane >> 3;    // 0..7 staging row within 8-row strip

  // XCD-bijective swizzle: 5504 = 8 * 688
  const int bid = blockIdx.x;
  const int swz = (bid & 7) * (NBMI * NBNI / 8) + (bid >> 3);
  const int bm = swz / NBNI;
  const int bn = swz % NBNI;

  // per-lane read base: row l15 (*128B), granule (lh ^ l7)*16B; ks flips bit 6
  const int rdBase0 = l15 * 128 + ((lh ^ l7) << 4);
  // staging: linear LDS dest <- pre-swizzled global source (granule = l7 ^ lr)
  const size_t srcOff = (size_t)lr * KDIM + ((l7 ^ lr) << 4);

  const char* aS = xq + ((size_t)(bm * 128 + w * 32)) * KDIM + srcOff;
  const char* bS = wq + ((size_t)(bn * 128 + w * 32)) * KDIM + srcOff;

  float bias_v[4];
#pragma unroll
  for (int n = 0; n < 4; ++n) bias_v[n] = bias[bn * 128 + wc * 64 + n * 16 + l15];

  f32x4 accf[4][4];
  int4v acci[4][4];
#pragma unroll
  for (int m = 0; m < 4; ++m)
#pragma unroll
    for (int n = 0; n < 4; ++n) {
      accf[m][n] = (f32x4){0.f, 0.f, 0.f, 0.f};
      acci[m][n] = (int4v){0, 0, 0, 0};
    }

#define STAGE8(cur, kt) {                                                      \
  _Pragma("unroll")                                                            \
  for (int s = 0; s < 4; ++s)                                                  \
    GLDS16(aS + (size_t)s * 8 * KDIM + (kt) * BKI,                             \
           ldsA + (cur) * 16384 + w * 4096 + s * 1024);                        \
  _Pragma("unroll")                                                            \
  for (int s = 0; s < 4; ++s)                                                  \
    GLDS16(bS + (size_t)s * 8 * KDIM + (kt) * BKI,                             \
           ldsB + (cur) * 16384 + w * 4096 + s * 1024); }

#define RD_A(cur, m, ks) (*(const int4v*)(ldsA + (cur) * 16384 + wr * 8192 +   \
                          (m) * 2048 + (rdBase0 ^ ((ks) * 64))))
#define RD_B(cur, n, ks) (*(const int4v*)(ldsB + (cur) * 16384 + wc * 8192 +   \
                          (n) * 2048 + (rdBase0 ^ ((ks) * 64))))

// One K-tile (BK=128): 2 ks-halves of 16 MFMA; one vmcnt(0)+barrier per tile.
// DOFIX on odd kt: apply group scales (g = kt>>1) to acci -> accf, reset acci.
#define TILE(cur, kt, DOSTAGE, DOFIX) {                                        \
  if (DOSTAGE) STAGE8((cur) ^ 1, (kt) + 1);                                    \
  int4v a0[4], b0[4], a1[4], b1[4];                                            \
  _Pragma("unroll")                                                            \
  for (int i = 0; i < 4; ++i) a0[i] = RD_A(cur, i, 0);                         \
  _Pragma("unroll")                                                            \
  for (int n = 0; n < 4; ++n) b0[n] = RD_B(cur, n, 0);                         \
  float4v sxv[4]; float swv[4];                                                \
  if (DOFIX) {                                                                 \
    const int g = (kt) >> 1;                                                   \
    _Pragma("unroll")                                                          \
    for (int m = 0; m < 4; ++m)                                                \
      sxv[m] = *(const float4v*)(sxT + (size_t)g * MDIM + bm * 128 + wr * 64 + \
                                 m * 16 + lh * 4);                             \
    _Pragma("unroll")                                                          \
    for (int n = 0; n < 4; ++n)                                                \
      swv[n] = swinv[(size_t)(bn * 128 + wc * 64 + n * 16 + l15) * 16 + g];    \
  }                                                                            \
  __builtin_amdgcn_s_setprio(1);                                               \
  _Pragma("unroll")                                                            \
  for (int m = 0; m < 4; ++m)                                                  \
    _Pragma("unroll")                                                          \
    for (int n = 0; n < 4; ++n)                                                \
      acci[m][n] = __builtin_amdgcn_mfma_i32_16x16x64_i8(a0[m], b0[n],         \
                                                         acci[m][n], 0, 0, 0); \
  __builtin_amdgcn_s_setprio(0);                                               \
  _Pragma("unroll")                                                            \
  for (int i = 0; i < 4; ++i) a1[i] = RD_A(cur, i, 1);                         \
  _Pragma("unroll")                                                            \
  for (int n = 0; n < 4; ++n) b1[n] = RD_B(cur, n, 1);                         \
  __builtin_amdgcn_s_setprio(1);                                               \
  _Pragma("unroll")                                                            \
  for (int m = 0; m < 4; ++m)                                                  \
    _Pragma("unroll")                                                          \
    for (int n = 0; n < 4; ++n)                                                \
      acci[m][n] = __builtin_amdgcn_mfma_i32_16x16x64_i8(a1[m], b1[n],         \
                                                         acci[m][n], 0, 0, 0); \
  __builtin_amdgcn_s_setprio(0);                                               \
  if (DOFIX) {                                                                 \
    _Pragma("unroll")                                                          \
    for (int m = 0; m < 4; ++m)                                                \
      _Pragma("unroll")                                                        \
      for (int n = 0; n < 4; ++n) {                                            \
        _Pragma("unroll")                                                      \
        for (int j = 0; j < 4; ++j)                                            \
          accf[m][n][j] += (float)acci[m][n][j] * (sxv[m][j] * swv[n]);        \
        acci[m][n] = (int4v){0, 0, 0, 0};                                      \
      }                                                                        \
  }                                                                            \
  asm volatile("s_waitcnt vmcnt(0)" ::: "memory");                             \
  __builtin_amdgcn_s_barrier(); }

  // prologue: stage tile 0, drain, barrier
  STAGE8(0, 0);
  asm volatile("s_waitcnt vmcnt(0)" ::: "memory");
  __builtin_amdgcn_s_barrier();

  for (int kt = 0; kt < NTI - 2; kt += 2) {
    TILE(0, kt, 1, 0)
    TILE(1, kt + 1, 1, 1)
  }
  TILE(0, NTI - 2, 1, 0)
  TILE(1, NTI - 1, 0, 1)

  // epilogue: bias + fp32 store (C/D map: col=lane&15, row=(lane>>4)*4+j)
#pragma unroll
  for (int m = 0; m < 4; ++m) {
    const int row0 = bm * 128 + wr * 64 + m * 16 + lh * 4;
#pragma unroll
    for (int n = 0; n < 4; ++n) {
      const int col = bn * 128 + wc * 64 + n * 16 + l15;
      const float bv_ = bias_v[n];
#pragma unroll
      for (int j = 0; j < 4; ++j)
        out[(size_t)(row0 + j) * NDIM + col] = accf[m][n][j] + bv_;
    }
  }
#undef TILE
#undef RD_A
#undef RD_B
#undef STAGE8
}

// ---------------- fallback: fused single-pass (round-1 kernel) ----------------
__global__ __launch_bounds__(256, 2) void clinear_fused(
    const float* __restrict__ x,
    const int* __restrict__ qw,
    const float* __restrict__ scale,
    const float* __restrict__ bias,
    float* __restrict__ out)
{
  __shared__ unsigned char ldsA[128 * 64 * 2];
  __shared__ unsigned char ldsB[128 * 64 * 2];

  const int t = threadIdx.x;
  const int lane = t & 63;
  const int wave = t >> 6;
  const int wr = wave >> 1;
  const int wc = wave & 1;

  const int NBN = NDIM / 128;
  const int bid = blockIdx.x;
  const int cpx = ((MDIM / 128) * NBN) >> 3;
  const int swz = (bid & 7) * cpx + (bid >> 3);
  const int bm = swz / NBN;
  const int bn = swz % NBN;

  const int srow = t >> 1;
  const int shalf = t & 1;
  const float* aptr = x  + (size_t)(bm * 128 + srow) * KDIM + shalf * 32;
  const int*   bptr = qw + (size_t)(bn * 128 + srow) * KDIM + shalf * 32;
  const float* sptr = scale + (size_t)(bn * 128 + srow) * (KDIM / 256);
  const int arx = srow & 7;

  f32x4 acc[4][4];
#pragma unroll
  for (int i = 0; i < 4; ++i)
#pragma unroll
    for (int j = 0; j < 4; ++j)
      acc[i][j] = (f32x4){0.f, 0.f, 0.f, 0.f};

  float bias_v[4];
#pragma unroll
  for (int n = 0; n < 4; ++n)
    bias_v[n] = bias[bn * 128 + wc * 64 + n * 16 + (lane & 15)];

  for (int kt = 0; kt < KDIM / 64; ++kt) {
    const int k0 = kt * 64;
    float4v av[8];
    int4v   bv[8];
#pragma unroll
    for (int j = 0; j < 8; ++j) av[j] = *(const float4v*)(aptr + k0 + 4 * j);
#pragma unroll
    for (int j = 0; j < 8; ++j) bv[j] = *(const int4v*)(bptr + k0 + 4 * j);
    const float inv = 1.0f / sptr[k0 >> 8];

    __syncthreads();
#pragma unroll
    for (int c = 0; c < 4; ++c) {
      short8 pa, pb;
#pragma unroll
      for (int e = 0; e < 8; ++e) {
        const int v = c * 8 + e;
        pa[e] = (short)f2bf(av[v >> 2][v & 3]);
        pb[e] = (short)f2bf((float)bv[v >> 2][v & 3] * inv);
      }
      const int cc = shalf * 4 + c;
      *(short8*)(ldsA + srow * 128 + ((cc ^ arx) << 4)) = pa;
      *(short8*)(ldsB + srow * 128 + ((cc ^ arx) << 4)) = pb;
    }
    __syncthreads();

    short8 af[4][2], bfr[4][2];
#pragma unroll
    for (int m = 0; m < 4; ++m) {
      const int r = wr * 64 + m * 16 + (lane & 15);
      const int rx = r & 7;
#pragma unroll
      for (int ks = 0; ks < 2; ++ks) {
        const int ch = ks * 4 + (lane >> 4);
        af[m][ks] = *(const short8*)(ldsA + r * 128 + ((ch ^ rx) << 4));
      }
    }
#pragma unroll
    for (int n = 0; n < 4; ++n) {
      const int r = wc * 64 + n * 16 + (lane & 15);
      const int rx = r & 7;
#pragma unroll
      for (int ks = 0; ks < 2; ++ks) {
        const int ch = ks * 4 + (lane >> 4);
        bfr[n][ks] = *(const short8*)(ldsB + r * 128 + ((ch ^ rx) << 4));
      }
    }
#pragma unroll
    for (int ks = 0; ks < 2; ++ks)
#pragma unroll
      for (int m = 0; m < 4; ++m)
#pragma unroll
        for (int n = 0; n < 4; ++n)
          acc[m][n] = __builtin_amdgcn_mfma_f32_16x16x32_bf16(
              af[m][ks], bfr[n][ks], acc[m][n], 0, 0, 0);
  }

#pragma unroll
  for (int m = 0; m < 4; ++m) {
    const int row0 = bm * 128 + wr * 64 + m * 16 + (lane >> 4) * 4;
#pragma unroll
    for (int n = 0; n < 4; ++n) {
      const int col = bn * 128 + wc * 64 + n * 16 + (lane & 15);
      const float bv_ = bias_v[n];
#pragma unroll
      for (int j = 0; j < 4; ++j)
        out[(size_t)(row0 + j) * NDIM + col] = acc[m][n][j] + bv_;
    }
  }
}

extern "C" void kernel_launch(void* const* d_in, const int* in_sizes, int n_in,
                              void* d_out, int out_size, void* d_ws, size_t ws_size,
                              hipStream_t stream) {
  const float* x     = (const float*)d_in[0];
  const int*   qw    = (const int*)d_in[1];
  const float* scale = (const float*)d_in[2];
  const float* bias  = (const float*)d_in[3];
  float* out = (float*)d_out;

  if (ws_size >= WS_NEED) {
    char*  xqb  = (char*)d_ws + XQ_OFF;
    char*  wqb  = (char*)d_ws + WQ_OFF;
    float* sxT  = (float*)((char*)d_ws + SXT_OFF);
    float* swi  = (float*)((char*)d_ws + SWI_OFF);
    hipLaunchKernelGGL(prep_all, dim3(MDIM + NDIM), dim3(256), 0, stream,
                       x, xqb, sxT, qw, scale, wqb, swi);
    hipLaunchKernelGGL(gemm_i8, dim3(NBMI * NBNI), dim3(256), 0, stream,
                       xqb, wqb, sxT, swi, bias, out);
  } else {
    hipLaunchKernelGGL(clinear_fused, dim3((MDIM / 128) * (NDIM / 128)), dim3(256),
                       0, stream, x, qw, scale, bias, out);
  }
}

// Round 9
// 616.024 us; speedup vs baseline: 1.2610x; 1.0397x over previous
//
#include <hip/hip_runtime.h>
#include <hip/hip_bf16.h>
#include <stdint.h>

typedef __attribute__((ext_vector_type(8))) short short8;
typedef __attribute__((ext_vector_type(4))) float f32x4;
typedef __attribute__((ext_vector_type(4))) float float4v;
typedef __attribute__((ext_vector_type(4))) int int4v;

#define MDIM 8192
#define NDIM 11008
#define KDIM 4096
#define BKI  64                /* i8 K-tile (bytes per LDS row) */
#define NTI  (KDIM / BKI)      /* 64 K-tiles */
#define NBMI (MDIM / 128)      /* 64 */
#define NBNI (NDIM / 128)      /* 86 */

// ws layout (bytes)
#define XQ_OFF  0ull
#define WQ_OFF  ((size_t)MDIM * KDIM)                 /* 33554432 */
#define SXT_OFF (WQ_OFF + (size_t)NDIM * KDIM)        /* + 45088768 */
#define SWT_OFF (SXT_OFF + 16ull * MDIM * 4)          /* + 524288 */
#define WS_NEED (SWT_OFF + 16ull * NDIM * 4)          /* ~79.9 MB */

static __device__ __forceinline__ unsigned short f2bf(float f) {
  union { float f; unsigned int u; } v;
  v.f = f;
  unsigned int r = v.u + 0x7FFFu + ((v.u >> 16) & 1u);
  return (unsigned short)(r >> 16);
}

#define GLDS16(g, l) __builtin_amdgcn_global_load_lds(                         \
    (const __attribute__((address_space(1))) void*)(g),                        \
    (__attribute__((address_space(3))) void*)(l), 16, 0, 0)

// ---------------- pass 1 (fused): x -> int8 groups  |  qweight -> int8 pack --
// blocks [0, MDIM): quantize x row; blocks [MDIM, MDIM+NDIM): pack w row.
// sxT layout [g][MDIM]; swT layout [g][NDIM]  (both transposed for staging).
__global__ __launch_bounds__(256) void prep_all(
    const float* __restrict__ x, char* __restrict__ xq, float* __restrict__ sxT,
    const int* __restrict__ qw, const float* __restrict__ scale,
    char* __restrict__ wq, float* __restrict__ swT) {
  const int t = threadIdx.x;
  if (blockIdx.x < MDIM) {
    const int row = blockIdx.x;
    const float* p = x + (size_t)row * KDIM + t * 16;
    float4v v[4];
#pragma unroll
    for (int c = 0; c < 4; ++c) v[c] = *(const float4v*)(p + c * 4);
    float amax = 0.f;
#pragma unroll
    for (int c = 0; c < 4; ++c)
#pragma unroll
      for (int e = 0; e < 4; ++e) amax = fmaxf(amax, fabsf(v[c][e]));
#pragma unroll
    for (int d = 1; d < 16; d <<= 1) amax = fmaxf(amax, __shfl_xor(amax, d));
    amax = fmaxf(amax, 1e-20f);
    if ((t & 15) == 0)
      sxT[(size_t)(t >> 4) * MDIM + row] = amax * (1.0f / 127.0f);
    const float inv = 127.0f / amax;
    int4v o;
#pragma unroll
    for (int c = 0; c < 4; ++c) {
      unsigned int r = 0;
#pragma unroll
      for (int e = 0; e < 4; ++e) {
        int q = __float2int_rn(v[c][e] * inv);
        r |= ((unsigned int)(q & 255)) << (8 * e);
      }
      o[c] = (int)r;
    }
    *(int4v*)(xq + (size_t)row * KDIM + t * 16) = o;
  } else {
    const int row = blockIdx.x - MDIM;
    const int* p = qw + (size_t)row * KDIM + t * 16;
    int4v v[4];
#pragma unroll
    for (int c = 0; c < 4; ++c) v[c] = *(const int4v*)(p + c * 4);
    int4v o;
#pragma unroll
    for (int c = 0; c < 4; ++c) {
      unsigned int r = 0;
#pragma unroll
      for (int e = 0; e < 4; ++e) r |= ((unsigned int)(v[c][e] & 255)) << (8 * e);
      o[c] = (int)r;
    }
    *(int4v*)(wq + (size_t)row * KDIM + t * 16) = o;
    if ((t & 15) == 0)
      swT[(size_t)(t >> 4) * NDIM + row] = 1.0f / scale[(size_t)row * 16 + (t >> 4)];
  }
}

// ---------------- pass 2: 128x128 i8 GEMM, BK=64, 4-deep counted-vmcnt ------
// 4 waves, wave tile 64x64. 4 LDS buffers (prefetch distance 3); steady-state
// wait vmcnt(8) (2 tiles always in flight); tail drains 8->4->0. Group-scale
// fixup reads from LDS (staged in prologue) so NO global loads touch vmcnt
// inside the K-loop. 80 KiB LDS -> 2 blocks/CU.
__global__ __launch_bounds__(256, 2) void gemm_i8(
    const char* __restrict__ xq, const char* __restrict__ wq,
    const float* __restrict__ sxT, const float* __restrict__ swT,
    const float* __restrict__ bias, float* __restrict__ out)
{
  __shared__ unsigned char lds[81920];
  unsigned char* ldsA = lds;              // [4][8192]: 128 rows x 64B
  unsigned char* ldsB = lds + 32768;      // [4][8192]
  float* sxl = (float*)(lds + 65536);     // [16][128] row scales
  float* swl = (float*)(lds + 73728);     // [16][128] col inv-scales

  const int t = threadIdx.x;
  const int lane = t & 63;
  const int w = t >> 6;        // wave 0..3
  const int wr = w >> 1;       // 0..1  (A 64-row half)
  const int wc = w & 1;        // 0..1  (B 64-col half)
  const int lh = lane >> 4;    // 0..3
  const int l15 = lane & 15;

  // XCD-bijective swizzle: 5504 = 8 * 688
  const int bid = blockIdx.x;
  const int swz = (bid & 7) * (NBMI * NBNI / 8) + (bid >> 3);
  const int bm = swz / NBNI;
  const int bn = swz % NBNI;

  // read swizzle: row r (0..15 within 16-row frag) holds logical granule q at
  // phys granule q ^ f(r), f(r) = (r&3)^(r>>2). 2-way bank aliasing max (free).
  const int f15 = (l15 & 3) ^ (l15 >> 2);
  const int rdGran = (lh ^ f15) << 4;
  // staging: linear LDS dest (lane*16) <- pre-swizzled global source
  const int srow16 = lane >> 2;                       // 0..15 row within strip
  const int q = (lane & 3) ^ (srow16 & 3) ^ ((srow16 >> 2) & 3);
  const size_t srcOff = (size_t)srow16 * KDIM + q * 16;

  const char* aS = xq + ((size_t)(bm * 128 + w * 32)) * KDIM + srcOff;
  const char* bS = wq + ((size_t)(bn * 128 + w * 32)) * KDIM + srcOff;

  // ---- prologue 1: stage scale tables into LDS (vmcnt quiet afterwards) ----
  {
    const int tg = t >> 4;                 // group 0..15
    const int tc = (t & 15) * 8;           // 8 floats each
    float4v a0 = *(const float4v*)(sxT + (size_t)tg * MDIM + bm * 128 + tc);
    float4v a1 = *(const float4v*)(sxT + (size_t)tg * MDIM + bm * 128 + tc + 4);
    float4v b0 = *(const float4v*)(swT + (size_t)tg * NDIM + bn * 128 + tc);
    float4v b1 = *(const float4v*)(swT + (size_t)tg * NDIM + bn * 128 + tc + 4);
    *(float4v*)(sxl + tg * 128 + tc)     = a0;
    *(float4v*)(sxl + tg * 128 + tc + 4) = a1;
    *(float4v*)(swl + tg * 128 + tc)     = b0;
    *(float4v*)(swl + tg * 128 + tc + 4) = b1;
  }
  __syncthreads();   // scale tables visible; no staging loads outstanding yet

  float bias_v[4];
#pragma unroll
  for (int n = 0; n < 4; ++n) bias_v[n] = bias[bn * 128 + wc * 64 + n * 16 + l15];

  f32x4 accf[4][4];
  int4v acci[4][4];
#pragma unroll
  for (int m = 0; m < 4; ++m)
#pragma unroll
    for (int n = 0; n < 4; ++n) {
      accf[m][n] = (f32x4){0.f, 0.f, 0.f, 0.f};
      acci[m][n] = (int4v){0, 0, 0, 0};
    }

  // 4 loads/wave/tile: A strips (w*32, w*32+16), B strips same
#define STAGE(buf, kt) {                                                       \
  GLDS16(aS + (kt) * BKI,              ldsA + (buf) * 8192 + w * 2048);        \
  GLDS16(aS + 16 * KDIM + (kt) * BKI,  ldsA + (buf) * 8192 + w * 2048 + 1024); \
  GLDS16(bS + (kt) * BKI,              ldsB + (buf) * 8192 + w * 2048);        \
  GLDS16(bS + 16 * KDIM + (kt) * BKI,  ldsB + (buf) * 8192 + w * 2048 + 1024); }

#define RD_A(buf, m) (*(const int4v*)(ldsA + (buf) * 8192 + wr * 4096 +        \
                      (m) * 1024 + l15 * 64 + rdGran))
#define RD_B(buf, n) (*(const int4v*)(ldsB + (buf) * 8192 + wc * 4096 +        \
                      (n) * 1024 + l15 * 64 + rdGran))

#define VMW(N) asm volatile("s_waitcnt vmcnt(" N ")" ::: "memory");

// tile t (buf = t&3): optionally stage tile t+3 into buf (t+3)&3; read frags;
// 16 MFMA; fixup on t%4==3 (g = t>>2, scales from LDS -> lgkmcnt domain);
// counted wait + barrier.
#define TILE(buf, kt, DOSTAGE, DOFIX, WAIT, DOBAR) {                           \
  if (DOSTAGE) STAGE(((buf) + 3) & 3, (kt) + 3);                               \
  int4v a[4], b[4];                                                            \
  _Pragma("unroll")                                                            \
  for (int i = 0; i < 4; ++i) a[i] = RD_A(buf, i);                             \
  _Pragma("unroll")                                                            \
  for (int n = 0; n < 4; ++n) b[n] = RD_B(buf, n);                             \
  float4v sxv[4]; float swv[4];                                                \
  if (DOFIX) {                                                                 \
    const int g = (kt) >> 2;                                                   \
    _Pragma("unroll")                                                          \
    for (int m = 0; m < 4; ++m)                                                \
      sxv[m] = *(const float4v*)(sxl + g * 128 + wr * 64 + m * 16 + lh * 4);   \
    _Pragma("unroll")                                                          \
    for (int n = 0; n < 4; ++n)                                                \
      swv[n] = swl[g * 128 + wc * 64 + n * 16 + l15];                          \
  }                                                                            \
  __builtin_amdgcn_s_setprio(1);                                               \
  _Pragma("unroll")                                                            \
  for (int m = 0; m < 4; ++m)                                                  \
    _Pragma("unroll")                                                          \
    for (int n = 0; n < 4; ++n)                                                \
      acci[m][n] = __builtin_amdgcn_mfma_i32_16x16x64_i8(a[m], b[n],           \
                                                         acci[m][n], 0, 0, 0); \
  __builtin_amdgcn_s_setprio(0);                                               \
  if (DOFIX) {                                                                 \
    _Pragma("unroll")                                                          \
    for (int m = 0; m < 4; ++m)                                                \
      _Pragma("unroll")                                                        \
      for (int n = 0; n < 4; ++n) {                                            \
        _Pragma("unroll")                                                      \
        for (int j = 0; j < 4; ++j)                                            \
          accf[m][n][j] += (float)acci[m][n][j] * (sxv[m][j] * swv[n]);        \
        acci[m][n] = (int4v){0, 0, 0, 0};                                      \
      }                                                                        \
  }                                                                            \
  WAIT                                                                         \
  if (DOBAR) __builtin_amdgcn_s_barrier(); }

  // ---- prologue 2: stage tiles 0,1,2 (12 loads); drain tile 0; publish ----
  STAGE(0, 0);
  STAGE(1, 1);
  STAGE(2, 2);
  VMW("8")
  __builtin_amdgcn_s_barrier();

  // steady state: wait vmcnt(8) each tile (2 tiles stay in flight)
  for (int kt = 0; kt < NTI - 4; kt += 4) {
    TILE(0, kt,     1, 0, VMW("8"), 1)
    TILE(1, kt + 1, 1, 0, VMW("8"), 1)
    TILE(2, kt + 2, 1, 0, VMW("8"), 1)
    TILE(3, kt + 3, 1, 1, VMW("8"), 1)
  }
  // tail: tile 60 stages 63; then exact drains 8 -> 4 -> 0
  TILE(0, NTI - 4, 1, 0, VMW("8"), 1)
  TILE(1, NTI - 3, 0, 0, VMW("4"), 1)
  TILE(2, NTI - 2, 0, 0, VMW("0"), 1)
  TILE(3, NTI - 1, 0, 1, , 0)

  // epilogue: bias + fp32 store (C/D map: col=lane&15, row=(lane>>4)*4+j)
#pragma unroll
  for (int m = 0; m < 4; ++m) {
    const int row0 = bm * 128 + wr * 64 + m * 16 + lh * 4;
#pragma unroll
    for (int n = 0; n < 4; ++n) {
      const int col = bn * 128 + wc * 64 + n * 16 + l15;
      const float bv_ = bias_v[n];
#pragma unroll
      for (int j = 0; j < 4; ++j)
        out[(size_t)(row0 + j) * NDIM + col] = accf[m][n][j] + bv_;
    }
  }
#undef TILE
#undef VMW
#undef RD_A
#undef RD_B
#undef STAGE
}

// ---------------- fallback: fused single-pass (round-1 kernel) ----------------
__global__ __launch_bounds__(256, 2) void clinear_fused(
    const float* __restrict__ x,
    const int* __restrict__ qw,
    const float* __restrict__ scale,
    const float* __restrict__ bias,
    float* __restrict__ out)
{
  __shared__ unsigned char ldsA[128 * 64 * 2];
  __shared__ unsigned char ldsB[128 * 64 * 2];

  const int t = threadIdx.x;
  const int lane = t & 63;
  const int wave = t >> 6;
  const int wr = wave >> 1;
  const int wc = wave & 1;

  const int NBN = NDIM / 128;
  const int bid = blockIdx.x;
  const int cpx = ((MDIM / 128) * NBN) >> 3;
  const int swz = (bid & 7) * cpx + (bid >> 3);
  const int bm = swz / NBN;
  const int bn = swz % NBN;

  const int srow = t >> 1;
  const int shalf = t & 1;
  const float* aptr = x  + (size_t)(bm * 128 + srow) * KDIM + shalf * 32;
  const int*   bptr = qw + (size_t)(bn * 128 + srow) * KDIM + shalf * 32;
  const float* sptr = scale + (size_t)(bn * 128 + srow) * (KDIM / 256);
  const int arx = srow & 7;

  f32x4 acc[4][4];
#pragma unroll
  for (int i = 0; i < 4; ++i)
#pragma unroll
    for (int j = 0; j < 4; ++j)
      acc[i][j] = (f32x4){0.f, 0.f, 0.f, 0.f};

  float bias_v[4];
#pragma unroll
  for (int n = 0; n < 4; ++n)
    bias_v[n] = bias[bn * 128 + wc * 64 + n * 16 + (lane & 15)];

  for (int kt = 0; kt < KDIM / 64; ++kt) {
    const int k0 = kt * 64;
    float4v av[8];
    int4v   bv[8];
#pragma unroll
    for (int j = 0; j < 8; ++j) av[j] = *(const float4v*)(aptr + k0 + 4 * j);
#pragma unroll
    for (int j = 0; j < 8; ++j) bv[j] = *(const int4v*)(bptr + k0 + 4 * j);
    const float inv = 1.0f / sptr[k0 >> 8];

    __syncthreads();
#pragma unroll
    for (int c = 0; c < 4; ++c) {
      short8 pa, pb;
#pragma unroll
      for (int e = 0; e < 8; ++e) {
        const int v = c * 8 + e;
        pa[e] = (short)f2bf(av[v >> 2][v & 3]);
        pb[e] = (short)f2bf((float)bv[v >> 2][v & 3] * inv);
      }
      const int cc = shalf * 4 + c;
      *(short8*)(ldsA + srow * 128 + ((cc ^ arx) << 4)) = pa;
      *(short8*)(ldsB + srow * 128 + ((cc ^ arx) << 4)) = pb;
    }
    __syncthreads();

    short8 af[4][2], bfr[4][2];
#pragma unroll
    for (int m = 0; m < 4; ++m) {
      const int r = wr * 64 + m * 16 + (lane & 15);
      const int rx = r & 7;
#pragma unroll
      for (int ks = 0; ks < 2; ++ks) {
        const int ch = ks * 4 + (lane >> 4);
        af[m][ks] = *(const short8*)(ldsA + r * 128 + ((ch ^ rx) << 4));
      }
    }
#pragma unroll
    for (int n = 0; n < 4; ++n) {
      const int r = wc * 64 + n * 16 + (lane & 15);
      const int rx = r & 7;
#pragma unroll
      for (int ks = 0; ks < 2; ++ks) {
        const int ch = ks * 4 + (lane >> 4);
        bfr[n][ks] = *(const short8*)(ldsB + r * 128 + ((ch ^ rx) << 4));
      }
    }
#pragma unroll
    for (int ks = 0; ks < 2; ++ks)
#pragma unroll
      for (int m = 0; m < 4; ++m)
#pragma unroll
        for (int n = 0; n < 4; ++n)
          acc[m][n] = __builtin_amdgcn_mfma_f32_16x16x32_bf16(
              af[m][ks], bfr[n][ks], acc[m][n], 0, 0, 0);
  }

#pragma unroll
  for (int m = 0; m < 4; ++m) {
    const int row0 = bm * 128 + wr * 64 + m * 16 + (lane >> 4) * 4;
#pragma unroll
    for (int n = 0; n < 4; ++n) {
      const int col = bn * 128 + wc * 64 + n * 16 + (lane & 15);
      const float bv_ = bias_v[n];
#pragma unroll
      for (int j = 0; j < 4; ++j)
        out[(size_t)(row0 + j) * NDIM + col] = acc[m][n][j] + bv_;
    }
  }
}

extern "C" void kernel_launch(void* const* d_in, const int* in_sizes, int n_in,
                              void* d_out, int out_size, void* d_ws, size_t ws_size,
                              hipStream_t stream) {
  const float* x     = (const float*)d_in[0];
  const int*   qw    = (const int*)d_in[1];
  const float* scale = (const float*)d_in[2];
  const float* bias  = (const float*)d_in[3];
  float* out = (float*)d_out;

  if (ws_size >= WS_NEED) {
    char*  xqb = (char*)d_ws + XQ_OFF;
    char*  wqb = (char*)d_ws + WQ_OFF;
    float* sxT = (float*)((char*)d_ws + SXT_OFF);
    float* swT = (float*)((char*)d_ws + SWT_OFF);
    hipLaunchKernelGGL(prep_all, dim3(MDIM + NDIM), dim3(256), 0, stream,
                       x, xqb, sxT, qw, scale, wqb, swT);
    hipLaunchKernelGGL(gemm_i8, dim3(NBMI * NBNI), dim3(256), 0, stream,
                       xqb, wqb, sxT, swT, bias, out);
  } else {
    hipLaunchKernelGGL(clinear_fused, dim3((MDIM / 128) * (NDIM / 128)), dim3(256),
                       0, stream, x, qw, scale, bias, out);
  }
}